// Round 3
// baseline (521.885 us; speedup 1.0000x reference)
//
#include <hip/hip_runtime.h>
#include <math.h>

#define B 16
#define N 2000
#define D 25088           // 512*7*7
#define D4 6272           // D/4 (float4 per row)
#define PI2 1.570795f     // 3.14159/2, matches the torch-module constant
#define RPB 8             // memory rows per block in k_dots
#define DCHUNKS 2
#define C4 (D4 / DCHUNKS) // 3136 float4 per d-chunk
#define NCHUNK 25
#define NPER (N / NCHUNK) // 80

__device__ __forceinline__ float wave_sum(float v) {
#pragma unroll
    for (int off = 32; off > 0; off >>= 1) v += __shfl_xor(v, off, 64);
    return v;
}
__device__ __forceinline__ float wave_max(float v) {
#pragma unroll
    for (int off = 32; off > 0; off >>= 1) v = fmaxf(v, __shfl_xor(v, off, 64));
    return v;
}

// ---------------------------------------------------------------------------
// Kernel 1: dots[b][n] = key[b].mem[n] (raw key; normalization cancels in the
// cosine) and mn2[n] = ||mem[n]||^2. Register tile 8 rows x 16 b = 128 fp32
// accumulators. __launch_bounds__(256,2) -> 256-VGPR budget: the tile MUST
// stay in registers (R1/R2 showed VGPR_Count=60 with 64+ live accs = spill).
// ---------------------------------------------------------------------------
__global__ __launch_bounds__(256, 2) void k_dots(const float4* __restrict__ key,
                                                 const float4* __restrict__ mem,
                                                 float* __restrict__ dots,
                                                 float* __restrict__ mn2) {
    const int tid = threadIdx.x;
    const int n0  = blockIdx.x * RPB;
    const int c0  = blockIdx.y * C4;
    const float4* mrow = mem + (size_t)n0 * D4;

    float acc[RPB][B];
    float msq[RPB];
#pragma unroll
    for (int j = 0; j < RPB; ++j) {
        msq[j] = 0.f;
#pragma unroll
        for (int b = 0; b < B; ++b) acc[j][b] = 0.f;
    }

    for (int i = c0 + tid; i < c0 + C4; i += 256) {
        float4 mv[RPB];
#pragma unroll
        for (int j = 0; j < RPB; ++j) mv[j] = mrow[(size_t)j * D4 + i];
#pragma unroll
        for (int j = 0; j < RPB; ++j) {
            msq[j] = fmaf(mv[j].x, mv[j].x, msq[j]);
            msq[j] = fmaf(mv[j].y, mv[j].y, msq[j]);
            msq[j] = fmaf(mv[j].z, mv[j].z, msq[j]);
            msq[j] = fmaf(mv[j].w, mv[j].w, msq[j]);
        }
#pragma unroll
        for (int g = 0; g < 4; ++g) {  // b in groups of 4 to bound live kv regs
            float4 kv[4];
#pragma unroll
            for (int t = 0; t < 4; ++t) kv[t] = key[(size_t)(g * 4 + t) * D4 + i];
#pragma unroll
            for (int t = 0; t < 4; ++t) {
#pragma unroll
                for (int j = 0; j < RPB; ++j) {
                    float a = acc[j][g * 4 + t];
                    a = fmaf(kv[t].x, mv[j].x, a);
                    a = fmaf(kv[t].y, mv[j].y, a);
                    a = fmaf(kv[t].z, mv[j].z, a);
                    a = fmaf(kv[t].w, mv[j].w, a);
                    acc[j][g * 4 + t] = a;
                }
            }
        }
    }

    // Block reduction: wave shuffles (136 values), then cross-wave via LDS.
    __shared__ float lds[4][RPB * B + RPB];
    const int wv = tid >> 6, ln = tid & 63;
#pragma unroll
    for (int j = 0; j < RPB; ++j) {
#pragma unroll
        for (int b = 0; b < B; ++b) {
            float v = wave_sum(acc[j][b]);
            if (ln == 0) lds[wv][j * B + b] = v;
        }
        float v = wave_sum(msq[j]);
        if (ln == 0) lds[wv][RPB * B + j] = v;
    }
    __syncthreads();
    if (tid < RPB * B + RPB) {
        float v = lds[0][tid] + lds[1][tid] + lds[2][tid] + lds[3][tid];
        if (tid < RPB * B) {
            const int j = tid >> 4, b = tid & 15;
            unsafeAtomicAdd(&dots[(size_t)b * N + n0 + j], v);
        } else {
            unsafeAtomicAdd(&mn2[n0 + (tid - RPB * B)], v);
        }
    }
}

// ---------------------------------------------------------------------------
// Kernel 2: per-b softmax of tan(cos * PI/2). One block per b. Small.
// ---------------------------------------------------------------------------
__global__ __launch_bounds__(256, 2) void k_softmax(const float4* __restrict__ key,
                                                    const float* __restrict__ dots,
                                                    const float* __restrict__ mn2,
                                                    float* __restrict__ w) {
    const int b = blockIdx.x, tid = threadIdx.x;
    const int wv = tid >> 6, ln = tid & 63;
    __shared__ float t[N];
    __shared__ float redA[4], redB[4], redC[4];

    float s = 0.f;
    for (int i = tid; i < D4; i += 256) {
        float4 v = key[(size_t)b * D4 + i];
        s = fmaf(v.x, v.x, s);
        s = fmaf(v.y, v.y, s);
        s = fmaf(v.z, v.z, s);
        s = fmaf(v.w, v.w, s);
    }
    s = wave_sum(s);
    if (ln == 0) redA[wv] = s;
    __syncthreads();
    const float kn = fmaxf(sqrtf(redA[0] + redA[1] + redA[2] + redA[3]), 1e-8f);

    float mx = -1e30f;
    for (int n = tid; n < N; n += 256) {
        float mn  = fmaxf(sqrtf(mn2[n]), 1e-8f);
        float cs  = dots[(size_t)b * N + n] / (kn * mn);
        float tv  = tanf(cs * PI2);
        t[n] = tv;
        mx = fmaxf(mx, tv);
    }
    mx = wave_max(mx);
    if (ln == 0) redB[wv] = mx;
    __syncthreads();
    mx = fmaxf(fmaxf(redB[0], redB[1]), fmaxf(redB[2], redB[3]));

    float sum = 0.f;
    for (int n = tid; n < N; n += 256) {
        float e = expf(t[n] - mx);
        t[n] = e;
        sum += e;
    }
    sum = wave_sum(sum);
    if (ln == 0) redC[wv] = sum;
    __syncthreads();
    sum = redC[0] + redC[1] + redC[2] + redC[3];
    const float inv = 1.f / sum;
    for (int n = tid; n < N; n += 256) w[(size_t)b * N + n] = t[n] * inv;
}

// ---------------------------------------------------------------------------
// Kernel 3: out[b][d] = sum_n w[b][n] * mem[n][d]. Grid (25, NCHUNK).
// n-unroll 8 -> 8 float4 loads in flight; w tile in LDS (broadcast reads);
// fp32 HW atomics merge the NCHUNK partials.
// ---------------------------------------------------------------------------
__global__ __launch_bounds__(256, 2) void k_out(const float4* __restrict__ mem,
                                                const float* __restrict__ w,
                                                float* __restrict__ out) {
    const int tid = threadIdx.x;
    const int d4  = blockIdx.x * 256 + tid;
    const int n0  = blockIdx.y * NPER;

    __shared__ float wt[B * NPER];  // wt[b][n], 16 x 80
    for (int i = tid; i < B * NPER; i += 256)
        wt[i] = w[(size_t)(i / NPER) * N + n0 + (i % NPER)];
    __syncthreads();
    if (d4 >= D4) return;

    const float4* mp = mem + (size_t)n0 * D4 + d4;
    float4 acc[B];
#pragma unroll
    for (int b = 0; b < B; ++b) acc[b] = make_float4(0.f, 0.f, 0.f, 0.f);

    for (int n = 0; n < NPER; n += 8) {
        float4 mv[8];
#pragma unroll
        for (int u = 0; u < 8; ++u) mv[u] = mp[(size_t)(n + u) * D4];
#pragma unroll
        for (int b = 0; b < B; ++b) {
            float4 a = acc[b];
#pragma unroll
            for (int u = 0; u < 8; ++u) {
                const float wv = wt[b * NPER + n + u];
                a.x = fmaf(wv, mv[u].x, a.x);
                a.y = fmaf(wv, mv[u].y, a.y);
                a.z = fmaf(wv, mv[u].z, a.z);
                a.w = fmaf(wv, mv[u].w, a.w);
            }
            acc[b] = a;
        }
    }
#pragma unroll
    for (int b = 0; b < B; ++b) {
        float* op = out + (size_t)b * D + (size_t)d4 * 4;
        unsafeAtomicAdd(op + 0, acc[b].x);
        unsafeAtomicAdd(op + 1, acc[b].y);
        unsafeAtomicAdd(op + 2, acc[b].z);
        unsafeAtomicAdd(op + 3, acc[b].w);
    }
}

extern "C" void kernel_launch(void* const* d_in, const int* in_sizes, int n_in,
                              void* d_out, int out_size, void* d_ws, size_t ws_size,
                              hipStream_t stream) {
    const float* key = (const float*)d_in[0];   // [16, 512, 7, 7]
    const float* mem = (const float*)d_in[1];   // [2000, 512, 7, 7]
    float* out = (float*)d_out;                 // [16, 512, 7, 7]

    float* ws   = (float*)d_ws;
    float* dots = ws;                 // B*N = 32000
    float* mn2  = ws + (size_t)B * N; // N   =  2000
    float* w    = mn2 + N;            // B*N = 32000

    hipMemsetAsync(d_out, 0, (size_t)B * D * sizeof(float), stream);
    hipMemsetAsync(ws, 0, (size_t)(B * N + N) * sizeof(float), stream); // dots+mn2
    k_dots<<<dim3(N / RPB, DCHUNKS), 256, 0, stream>>>((const float4*)key, (const float4*)mem, dots, mn2);
    k_softmax<<<dim3(B), 256, 0, stream>>>((const float4*)key, dots, mn2, w);
    k_out<<<dim3((D4 + 255) / 256, NCHUNK), 256, 0, stream>>>((const float4*)mem, w, out);
}

// Round 4
// 383.012 us; speedup vs baseline: 1.3626x; 1.3626x over previous
//
#include <hip/hip_runtime.h>
#include <math.h>

#define B 16
#define N 2000
#define D 25088            // 512*7*7
#define D4 6272            // D/4
#define PI2 1.570795f      // 3.14159/2, matches the torch-module constant
#define KC 16              // K-chunks in k_dots (one per wave-tile column)
#define KSPAN (D / KC)     // 1568
#define KTILES (KSPAN / 32)// 49 MFMA k-steps per wave
#define NT (D / 32)        // 784 k-tiles total
#define NCHUNK 10
#define NPER (N / NCHUNK)  // 200

typedef __attribute__((ext_vector_type(8))) short short8;   // 8 x bf16 frag
typedef __attribute__((ext_vector_type(4))) float f32x4;    // MFMA C/D

__device__ __forceinline__ float wave_sum(float v) {
#pragma unroll
    for (int off = 32; off > 0; off >>= 1) v += __shfl_xor(v, off, 64);
    return v;
}
__device__ __forceinline__ float wave_max(float v) {
#pragma unroll
    for (int off = 32; off > 0; off >>= 1) v = fmaxf(v, __shfl_xor(v, off, 64));
    return v;
}

// ---------------------------------------------------------------------------
// k_split: key fp32 -> bf16 hi/lo planes, pre-swizzled into MFMA A-frag order:
// ksw[plane][tile][lane][8], lane holds A[m=lane&15][k=tile*32+(lane>>4)*8+j].
// hi = truncate-to-bf16(x), lo = truncate-to-bf16(x - hi): all error terms
// <= 2^-16 relative on positive data.
// ---------------------------------------------------------------------------
__global__ void k_split(const float* __restrict__ key, unsigned short* __restrict__ ksw) {
    const int g    = blockIdx.x * 256 + threadIdx.x;   // 0 .. NT*64-1
    const int tile = g >> 6, lane = g & 63;
    const int m = lane & 15, quad = lane >> 4;
    const float* src = key + (size_t)m * D + tile * 32 + quad * 8;
    float4 x0 = *(const float4*)src;
    float4 x1 = *(const float4*)(src + 4);
    float xs[8] = {x0.x, x0.y, x0.z, x0.w, x1.x, x1.y, x1.z, x1.w};
    unsigned short h[8], l[8];
#pragma unroll
    for (int j = 0; j < 8; ++j) {
        unsigned int u = __float_as_uint(xs[j]);
        h[j] = (unsigned short)(u >> 16);
        float lo = xs[j] - __uint_as_float(u & 0xFFFF0000u);
        l[j] = (unsigned short)(__float_as_uint(lo) >> 16);
    }
    unsigned short* dh = ksw + ((size_t)tile * 64 + lane) * 8;
    unsigned short* dl = ksw + ((size_t)(NT + tile) * 64 + lane) * 8;
#pragma unroll
    for (int j = 0; j < 8; ++j) { dh[j] = h[j]; dl[j] = l[j]; }
}

// ---------------------------------------------------------------------------
// k_dots (MFMA): dots[b][n] = key[b].mem[n], mn2[n] = ||mem[n]||^2.
// Grid (125, 4) x 4 waves: each wave owns a 16-row n-tile x 1/16th of K.
// 3 MFMA per k-step (hi*hi, hi*lo, lo*hi); fp32 msq on the side.
// Partials to dpart[kc][b][n] / mpart[kc][n] with plain stores (no atomics).
// ---------------------------------------------------------------------------
__global__ __launch_bounds__(256) void k_dots(const float* __restrict__ mem,
                                              const unsigned short* __restrict__ ksw,
                                              float* __restrict__ dpart,
                                              float* __restrict__ mpart) {
    const int tid  = threadIdx.x;
    const int lane = tid & 63;
    const int wave = tid >> 6;
    const int n0   = blockIdx.x * 16;
    const int kc   = blockIdx.y * 4 + wave;        // 0..15
    const int nrow = lane & 15, quad = lane >> 4;

    const float* mrow = mem + (size_t)(n0 + nrow) * D + kc * KSPAN + quad * 8;
    const short8* kh = (const short8*)(ksw + ((size_t)(kc * KTILES) * 64 + lane) * 8);
    const short8* kl = (const short8*)(ksw + ((size_t)(NT + kc * KTILES) * 64 + lane) * 8);

    f32x4 ahh = {0.f, 0.f, 0.f, 0.f};
    f32x4 ahl = ahh, alh = ahh;
    float msq = 0.f;

    for (int t = 0; t < KTILES; ++t) {
        float4 x0 = *(const float4*)(mrow + t * 32);
        float4 x1 = *(const float4*)(mrow + t * 32 + 4);
        short8 ah = kh[(size_t)t * 64];
        short8 al = kl[(size_t)t * 64];
        float xs[8] = {x0.x, x0.y, x0.z, x0.w, x1.x, x1.y, x1.z, x1.w};
        short8 bh, bl;
#pragma unroll
        for (int j = 0; j < 8; ++j) {
            unsigned int u = __float_as_uint(xs[j]);
            bh[j] = (short)(u >> 16);
            float lo = xs[j] - __uint_as_float(u & 0xFFFF0000u);
            bl[j] = (short)(__float_as_uint(lo) >> 16);
            msq = fmaf(xs[j], xs[j], msq);
        }
        ahh = __builtin_amdgcn_mfma_f32_16x16x32_bf16(ah, bh, ahh, 0, 0, 0);
        ahl = __builtin_amdgcn_mfma_f32_16x16x32_bf16(ah, bl, ahl, 0, 0, 0);
        alh = __builtin_amdgcn_mfma_f32_16x16x32_bf16(al, bh, alh, 0, 0, 0);
    }

    f32x4 dt;
#pragma unroll
    for (int r = 0; r < 4; ++r) dt[r] = ahh[r] + ahl[r] + alh[r];
    // C/D layout (m89-verified): col(n) = lane&15, row(b) = quad*4 + reg
#pragma unroll
    for (int r = 0; r < 4; ++r)
        dpart[((size_t)kc * B + quad * 4 + r) * N + n0 + nrow] = dt[r];

    msq += __shfl_xor(msq, 16, 64);
    msq += __shfl_xor(msq, 32, 64);
    if (quad == 0) mpart[(size_t)kc * N + n0 + nrow] = msq;
}

// ---------------------------------------------------------------------------
// k_softmax: reduce K-partials, then per-b softmax of tan(cos * PI/2).
// ---------------------------------------------------------------------------
__global__ __launch_bounds__(256, 2) void k_softmax(const float4* __restrict__ key,
                                                    const float* __restrict__ dpart,
                                                    const float* __restrict__ mpart,
                                                    float* __restrict__ w) {
    const int b = blockIdx.x, tid = threadIdx.x;
    const int wv = tid >> 6, ln = tid & 63;
    __shared__ float t[N];
    __shared__ float redA[4], redB[4], redC[4];

    float s = 0.f;
    for (int i = tid; i < D4; i += 256) {
        float4 v = key[(size_t)b * D4 + i];
        s = fmaf(v.x, v.x, s); s = fmaf(v.y, v.y, s);
        s = fmaf(v.z, v.z, s); s = fmaf(v.w, v.w, s);
    }
    s = wave_sum(s);
    if (ln == 0) redA[wv] = s;
    __syncthreads();
    const float kn = fmaxf(sqrtf(redA[0] + redA[1] + redA[2] + redA[3]), 1e-8f);

    float mx = -1e30f;
    for (int n = tid; n < N; n += 256) {
        float ds = 0.f, ms = 0.f;
#pragma unroll
        for (int kc = 0; kc < KC; ++kc) {
            ds += dpart[((size_t)kc * B + b) * N + n];
            ms += mpart[(size_t)kc * N + n];
        }
        float mn = fmaxf(sqrtf(ms), 1e-8f);
        float tv = tanf(ds / (kn * mn) * PI2);
        t[n] = tv;
        mx = fmaxf(mx, tv);
    }
    mx = wave_max(mx);
    if (ln == 0) redB[wv] = mx;
    __syncthreads();
    mx = fmaxf(fmaxf(redB[0], redB[1]), fmaxf(redB[2], redB[3]));

    float sum = 0.f;
    for (int n = tid; n < N; n += 256) {
        float e = expf(t[n] - mx);
        t[n] = e;
        sum += e;
    }
    sum = wave_sum(sum);
    if (ln == 0) redC[wv] = sum;
    __syncthreads();
    sum = redC[0] + redC[1] + redC[2] + redC[3];
    const float inv = 1.f / sum;
    for (int n = tid; n < N; n += 256) w[(size_t)b * N + n] = t[n] * inv;
}

// ---------------------------------------------------------------------------
// k_out partials: part[c][b][d] = sum_{n in chunk c} w[b][n] * mem[n][d].
// Grid (49, NCHUNK) x 128 thr; plain coalesced stores (NO atomics).
// ---------------------------------------------------------------------------
__global__ __launch_bounds__(128) void k_out_p(const float4* __restrict__ mem,
                                               const float* __restrict__ w,
                                               float4* __restrict__ part) {
    const int tid = threadIdx.x;
    const int d4  = blockIdx.x * 128 + tid;
    const int n0  = blockIdx.y * NPER;

    __shared__ float wt[B * NPER];
    for (int i = tid; i < B * NPER; i += 128)
        wt[i] = w[(size_t)(i / NPER) * N + n0 + (i % NPER)];
    __syncthreads();

    const float4* mp = mem + (size_t)n0 * D4 + d4;
    float4 acc[B];
#pragma unroll
    for (int b = 0; b < B; ++b) acc[b] = make_float4(0.f, 0.f, 0.f, 0.f);

    for (int n = 0; n < NPER; n += 8) {
        float4 mv[8];
#pragma unroll
        for (int u = 0; u < 8; ++u) mv[u] = mp[(size_t)(n + u) * D4];
#pragma unroll
        for (int b = 0; b < B; ++b) {
            float4 a = acc[b];
#pragma unroll
            for (int u = 0; u < 8; ++u) {
                const float wv = wt[b * NPER + n + u];
                a.x = fmaf(wv, mv[u].x, a.x); a.y = fmaf(wv, mv[u].y, a.y);
                a.z = fmaf(wv, mv[u].z, a.z); a.w = fmaf(wv, mv[u].w, a.w);
            }
            acc[b] = a;
        }
    }
#pragma unroll
    for (int b = 0; b < B; ++b)
        part[((size_t)blockIdx.y * B + b) * D4 + d4] = acc[b];
}

__global__ void k_reduce(const float4* __restrict__ part, float4* __restrict__ out) {
    const int i = blockIdx.x * 256 + threadIdx.x;   // < B*D4 = 100352
    float4 s = part[i];
#pragma unroll
    for (int c = 1; c < NCHUNK; ++c) {
        float4 p = part[(size_t)c * B * D4 + i];
        s.x += p.x; s.y += p.y; s.z += p.z; s.w += p.w;
    }
    out[i] = s;
}

// Atomic fallback for k_out if workspace is too small for partials.
__global__ __launch_bounds__(128) void k_out_atomic(const float4* __restrict__ mem,
                                                    const float* __restrict__ w,
                                                    float* __restrict__ out) {
    const int tid = threadIdx.x;
    const int d4  = blockIdx.x * 128 + tid;
    const int n0  = blockIdx.y * NPER;
    __shared__ float wt[B * NPER];
    for (int i = tid; i < B * NPER; i += 128)
        wt[i] = w[(size_t)(i / NPER) * N + n0 + (i % NPER)];
    __syncthreads();
    const float4* mp = mem + (size_t)n0 * D4 + d4;
    float4 acc[B];
#pragma unroll
    for (int b = 0; b < B; ++b) acc[b] = make_float4(0.f, 0.f, 0.f, 0.f);
    for (int n = 0; n < NPER; n += 8) {
        float4 mv[8];
#pragma unroll
        for (int u = 0; u < 8; ++u) mv[u] = mp[(size_t)(n + u) * D4];
#pragma unroll
        for (int b = 0; b < B; ++b) {
            float4 a = acc[b];
#pragma unroll
            for (int u = 0; u < 8; ++u) {
                const float wv = wt[b * NPER + n + u];
                a.x = fmaf(wv, mv[u].x, a.x); a.y = fmaf(wv, mv[u].y, a.y);
                a.z = fmaf(wv, mv[u].z, a.z); a.w = fmaf(wv, mv[u].w, a.w);
            }
            acc[b] = a;
        }
    }
#pragma unroll
    for (int b = 0; b < B; ++b) {
        float* op = out + (size_t)b * D + (size_t)d4 * 4;
        unsafeAtomicAdd(op + 0, acc[b].x);
        unsafeAtomicAdd(op + 1, acc[b].y);
        unsafeAtomicAdd(op + 2, acc[b].z);
        unsafeAtomicAdd(op + 3, acc[b].w);
    }
}

extern "C" void kernel_launch(void* const* d_in, const int* in_sizes, int n_in,
                              void* d_out, int out_size, void* d_ws, size_t ws_size,
                              hipStream_t stream) {
    const float* key = (const float*)d_in[0];   // [16, 512, 7, 7]
    const float* mem = (const float*)d_in[1];   // [2000, 512, 7, 7]
    float* out = (float*)d_out;                 // [16, 512, 7, 7]

    // Workspace layout (floats). ksw first (16B-aligned), then partials.
    float* ws = (float*)d_ws;
    unsigned short* ksw = (unsigned short*)ws;          // 2*NT*64*8 ushorts = 1.6 MB
    float* dpart = ws + 401408;                         // KC*B*N  = 512000
    float* mpart = dpart + (size_t)KC * B * N;          // KC*N    =  32000
    float* w     = mpart + (size_t)KC * N;              // B*N     =  32000
    float* part  = w + (size_t)B * N;                   // NCHUNK*B*D = 4014080
    const size_t need_full = (size_t)(401408 + KC * B * N + KC * N + B * N + NCHUNK * B * D) * 4;

    k_split<<<dim3(NT * 64 / 256), 256, 0, stream>>>(key, ksw);
    k_dots<<<dim3(N / 16, 4), 256, 0, stream>>>(mem, ksw, dpart, mpart);
    k_softmax<<<dim3(B), 256, 0, stream>>>((const float4*)key, dpart, mpart, w);
    if (ws_size >= need_full) {
        k_out_p<<<dim3(D4 / 128, NCHUNK), 128, 0, stream>>>((const float4*)mem, w, (float4*)part);
        k_reduce<<<dim3(B * D4 / 256), 256, 0, stream>>>((const float4*)part, (float4*)out);
    } else {
        hipMemsetAsync(d_out, 0, (size_t)B * D * sizeof(float), stream);
        k_out_atomic<<<dim3(D4 / 128, NCHUNK), 128, 0, stream>>>((const float4*)mem, w, out);
    }
}

// Round 5
// 359.279 us; speedup vs baseline: 1.4526x; 1.0661x over previous
//
#include <hip/hip_runtime.h>
#include <math.h>

#define B 16
#define N 2000
#define D 25088            // 512*7*7
#define D4 6272            // D/4
#define PI2 1.570795f      // 3.14159/2, matches the torch-module constant
#define KC 16              // K-chunks in k_dots (one per wave-tile column)
#define KSPAN (D / KC)     // 1568
#define KTILES (KSPAN / 32)// 49 MFMA k-steps per wave
#define NT (D / 32)        // 784 k-tiles total
#define NCHUNK 25
#define NPER (N / NCHUNK)  // 80
#define SELHI 0x07060302u  // v_perm selector: pack hi16(x0)|hi16(x1)<<16

typedef __attribute__((ext_vector_type(8))) short short8;   // 8 x bf16 frag
typedef __attribute__((ext_vector_type(4))) float f32x4;    // MFMA C/D
typedef unsigned int uint;

union pk { uint4 u; short8 s; };
__device__ __forceinline__ short8 as_s8(uint4 u) { pk p; p.u = u; return p.s; }

__device__ __forceinline__ float wave_sum(float v) {
#pragma unroll
    for (int off = 32; off > 0; off >>= 1) v += __shfl_xor(v, off, 64);
    return v;
}
__device__ __forceinline__ float wave_max(float v) {
#pragma unroll
    for (int off = 32; off > 0; off >>= 1) v = fmaxf(v, __shfl_xor(v, off, 64));
    return v;
}

// fp32x8 -> bf16 hi/lo fragments (truncation split, bit-identical to the
// shift version verified in R4) + msq accumulation. v_perm packs pairs.
__device__ __forceinline__ void cvt_hilo(const float4& a, const float4& b,
                                         short8& hi, short8& lo, float& msq) {
    float xs[8] = {a.x, a.y, a.z, a.w, b.x, b.y, b.z, b.w};
    uint lu[8];
#pragma unroll
    for (int j = 0; j < 8; ++j) {
        uint u = __float_as_uint(xs[j]);
        float lof = xs[j] - __uint_as_float(u & 0xffff0000u);
        lu[j] = __float_as_uint(lof);
        msq = fmaf(xs[j], xs[j], msq);
    }
    uint4 h, l;
    h.x = __builtin_amdgcn_perm(__float_as_uint(xs[1]), __float_as_uint(xs[0]), SELHI);
    h.y = __builtin_amdgcn_perm(__float_as_uint(xs[3]), __float_as_uint(xs[2]), SELHI);
    h.z = __builtin_amdgcn_perm(__float_as_uint(xs[5]), __float_as_uint(xs[4]), SELHI);
    h.w = __builtin_amdgcn_perm(__float_as_uint(xs[7]), __float_as_uint(xs[6]), SELHI);
    l.x = __builtin_amdgcn_perm(lu[1], lu[0], SELHI);
    l.y = __builtin_amdgcn_perm(lu[3], lu[2], SELHI);
    l.z = __builtin_amdgcn_perm(lu[5], lu[4], SELHI);
    l.w = __builtin_amdgcn_perm(lu[7], lu[6], SELHI);
    hi = as_s8(h); lo = as_s8(l);
}

// ---------------------------------------------------------------------------
// k_split: key fp32 -> bf16 hi/lo planes in MFMA A-frag order; fuses the
// per-b ||key||^2 reduction into kn2[16] (must be zeroed before launch).
// ---------------------------------------------------------------------------
__global__ void k_split(const float* __restrict__ key, unsigned short* __restrict__ ksw,
                        float* __restrict__ kn2) {
    const int tid  = threadIdx.x;
    const int g    = blockIdx.x * 256 + tid;   // 0 .. NT*64-1
    const int tile = g >> 6, lane = g & 63;
    const int m = lane & 15, quad = lane >> 4;
    const float* src = key + (size_t)m * D + tile * 32 + quad * 8;
    float4 x0 = *(const float4*)src;
    float4 x1 = *(const float4*)(src + 4);
    short8 hi, lo;
    float ssq = 0.f;
    cvt_hilo(x0, x1, hi, lo, ssq);
    pk ph; ph.s = hi;
    pk pl; pl.s = lo;
    *(uint4*)(ksw + ((size_t)tile * 64 + lane) * 8)        = ph.u;
    *(uint4*)(ksw + ((size_t)(NT + tile) * 64 + lane) * 8) = pl.u;

    // ||key_m||^2 partials: quad-reduce, then block-reduce, 16 atomics/block.
    ssq += __shfl_xor(ssq, 16, 64);
    ssq += __shfl_xor(ssq, 32, 64);
    __shared__ float lds[4][16];
    if (quad == 0) lds[tid >> 6][m] = ssq;
    __syncthreads();
    if (tid < 16)
        atomicAdd(&kn2[tid], lds[0][tid] + lds[1][tid] + lds[2][tid] + lds[3][tid]);
}

// ---------------------------------------------------------------------------
// k_dots (MFMA): dots[b][n] = key[b].mem[n], mn2[n] = ||mem[n]||^2.
// Grid (125, 4) x 4 waves; wave = 16-row n-tile x 1/16th of K. Register
// double-buffer: prefetch step t+1's loads before converting/MFMA-ing t.
// ---------------------------------------------------------------------------
__global__ __launch_bounds__(256, 2) void k_dots(const float* __restrict__ mem,
                                                 const unsigned short* __restrict__ ksw,
                                                 float* __restrict__ dpart,
                                                 float* __restrict__ mpart) {
    const int tid  = threadIdx.x;
    const int lane = tid & 63;
    const int wave = tid >> 6;
    const int n0   = blockIdx.x * 16;
    const int kc   = blockIdx.y * 4 + wave;        // 0..15
    const int nrow = lane & 15, quad = lane >> 4;

    const float4* mrow4 = (const float4*)(mem + (size_t)(n0 + nrow) * D + kc * KSPAN) + quad * 2;
    const uint4* khp = (const uint4*)(ksw + ((size_t)(kc * KTILES) * 64 + lane) * 8);
    const uint4* klp = (const uint4*)(ksw + ((size_t)(NT + kc * KTILES) * 64 + lane) * 8);

    f32x4 ahh = {0.f, 0.f, 0.f, 0.f};
    f32x4 ahl = ahh, alh = ahh;
    float msq = 0.f;

    float4 c0 = mrow4[0], c1 = mrow4[1];
    uint4 kah = khp[0],  kal = klp[0];

    for (int t = 0; t < KTILES; ++t) {
        const int tn = (t + 1 < KTILES) ? t + 1 : t;
        float4 p0 = mrow4[(size_t)tn * 8];
        float4 p1 = mrow4[(size_t)tn * 8 + 1];
        uint4 pah = khp[(size_t)tn * 64];
        uint4 pal = klp[(size_t)tn * 64];

        short8 bh, bl;
        cvt_hilo(c0, c1, bh, bl, msq);
        short8 ah = as_s8(kah), al = as_s8(kal);
        ahh = __builtin_amdgcn_mfma_f32_16x16x32_bf16(ah, bh, ahh, 0, 0, 0);
        ahl = __builtin_amdgcn_mfma_f32_16x16x32_bf16(ah, bl, ahl, 0, 0, 0);
        alh = __builtin_amdgcn_mfma_f32_16x16x32_bf16(al, bh, alh, 0, 0, 0);

        c0 = p0; c1 = p1; kah = pah; kal = pal;
    }

    f32x4 dt;
#pragma unroll
    for (int r = 0; r < 4; ++r) dt[r] = ahh[r] + ahl[r] + alh[r];
    // C/D layout (m89-verified): col(n) = lane&15, row(b) = quad*4 + reg
#pragma unroll
    for (int r = 0; r < 4; ++r)
        dpart[((size_t)kc * B + quad * 4 + r) * N + n0 + nrow] = dt[r];

    msq += __shfl_xor(msq, 16, 64);
    msq += __shfl_xor(msq, 32, 64);
    if (quad == 0) mpart[(size_t)kc * N + n0 + nrow] = msq;
}

// ---------------------------------------------------------------------------
// k_softmax: reduce K-partials, per-b softmax of tan(cos * PI/2).
// ---------------------------------------------------------------------------
__global__ __launch_bounds__(256, 2) void k_softmax(const float* __restrict__ kn2,
                                                    const float* __restrict__ dpart,
                                                    const float* __restrict__ mpart,
                                                    float* __restrict__ w) {
    const int b = blockIdx.x, tid = threadIdx.x;
    const int wv = tid >> 6, ln = tid & 63;
    __shared__ float t[N];
    __shared__ float redB[4], redC[4];

    const float kn = fmaxf(sqrtf(kn2[b]), 1e-8f);

    float mx = -1e30f;
    for (int n = tid; n < N; n += 256) {
        float ds = 0.f, ms = 0.f;
#pragma unroll
        for (int kc = 0; kc < KC; ++kc) {
            ds += dpart[((size_t)kc * B + b) * N + n];
            ms += mpart[(size_t)kc * N + n];
        }
        float mn = fmaxf(sqrtf(ms), 1e-8f);
        float tv = tanf(ds / (kn * mn) * PI2);
        t[n] = tv;
        mx = fmaxf(mx, tv);
    }
    mx = wave_max(mx);
    if (ln == 0) redB[wv] = mx;
    __syncthreads();
    mx = fmaxf(fmaxf(redB[0], redB[1]), fmaxf(redB[2], redB[3]));

    float sum = 0.f;
    for (int n = tid; n < N; n += 256) {
        float e = expf(t[n] - mx);
        t[n] = e;
        sum += e;
    }
    sum = wave_sum(sum);
    if (ln == 0) redC[wv] = sum;
    __syncthreads();
    sum = redC[0] + redC[1] + redC[2] + redC[3];
    const float inv = 1.f / sum;
    for (int n = tid; n < N; n += 256) w[(size_t)b * N + n] = t[n] * inv;
}

// ---------------------------------------------------------------------------
// k_out partials: part[c][b][d] = sum_{n in chunk c} w[b][n]*mem[n][d].
// Grid (25, NCHUNK) x 256 thr = 2500 waves (~10/CU); fully-unrolled 10-group
// loop with next-group prefetch (8 float4 in flight); plain stores.
// ---------------------------------------------------------------------------
__global__ __launch_bounds__(256, 2) void k_out_p(const float4* __restrict__ mem,
                                                  const float* __restrict__ w,
                                                  float4* __restrict__ part) {
    const int tid = threadIdx.x;
    const int d4  = blockIdx.x * 256 + tid;
    const int n0  = blockIdx.y * NPER;

    __shared__ float wt[B * NPER];   // 16 x 80
    for (int i = tid; i < B * NPER; i += 256)
        wt[i] = w[(size_t)(i / NPER) * N + n0 + (i % NPER)];
    __syncthreads();
    if (d4 >= D4) return;

    const float4* mp = mem + (size_t)n0 * D4 + d4;
    float4 acc[B];
#pragma unroll
    for (int b = 0; b < B; ++b) acc[b] = make_float4(0.f, 0.f, 0.f, 0.f);

    float4 cur[8];
#pragma unroll
    for (int u = 0; u < 8; ++u) cur[u] = mp[(size_t)u * D4];

#pragma unroll
    for (int g = 0; g < NPER / 8; ++g) {
        const int gn = (g + 1 < NPER / 8) ? g + 1 : g;
        float4 nxt[8];
#pragma unroll
        for (int u = 0; u < 8; ++u) nxt[u] = mp[(size_t)(gn * 8 + u) * D4];
#pragma unroll
        for (int b = 0; b < B; ++b) {
            float4 a = acc[b];
#pragma unroll
            for (int u = 0; u < 8; ++u) {
                const float wv = wt[b * NPER + g * 8 + u];
                a.x = fmaf(wv, cur[u].x, a.x); a.y = fmaf(wv, cur[u].y, a.y);
                a.z = fmaf(wv, cur[u].z, a.z); a.w = fmaf(wv, cur[u].w, a.w);
            }
            acc[b] = a;
        }
#pragma unroll
        for (int u = 0; u < 8; ++u) cur[u] = nxt[u];
    }
#pragma unroll
    for (int b = 0; b < B; ++b)
        part[((size_t)blockIdx.y * B + b) * D4 + d4] = acc[b];
}

__global__ void k_reduce(const float4* __restrict__ part, float4* __restrict__ out) {
    const int i = blockIdx.x * 256 + threadIdx.x;   // < B*D4 = 100352
    float4 s = part[i];
#pragma unroll
    for (int c = 1; c < NCHUNK; ++c) {
        float4 p = part[(size_t)c * B * D4 + i];
        s.x += p.x; s.y += p.y; s.z += p.z; s.w += p.w;
    }
    out[i] = s;
}

// Atomic fallback if workspace is too small for partials.
__global__ __launch_bounds__(256, 2) void k_out_atomic(const float4* __restrict__ mem,
                                                       const float* __restrict__ w,
                                                       float* __restrict__ out) {
    const int tid = threadIdx.x;
    const int d4  = blockIdx.x * 256 + tid;
    const int n0  = blockIdx.y * NPER;
    __shared__ float wt[B * NPER];
    for (int i = tid; i < B * NPER; i += 256)
        wt[i] = w[(size_t)(i / NPER) * N + n0 + (i % NPER)];
    __syncthreads();
    if (d4 >= D4) return;
    const float4* mp = mem + (size_t)n0 * D4 + d4;
    float4 acc[B];
#pragma unroll
    for (int b = 0; b < B; ++b) acc[b] = make_float4(0.f, 0.f, 0.f, 0.f);
    for (int n = 0; n < NPER; n += 8) {
        float4 mv[8];
#pragma unroll
        for (int u = 0; u < 8; ++u) mv[u] = mp[(size_t)(n + u) * D4];
#pragma unroll
        for (int b = 0; b < B; ++b) {
            float4 a = acc[b];
#pragma unroll
            for (int u = 0; u < 8; ++u) {
                const float wv = wt[b * NPER + n + u];
                a.x = fmaf(wv, mv[u].x, a.x); a.y = fmaf(wv, mv[u].y, a.y);
                a.z = fmaf(wv, mv[u].z, a.z); a.w = fmaf(wv, mv[u].w, a.w);
            }
            acc[b] = a;
        }
    }
#pragma unroll
    for (int b = 0; b < B; ++b) {
        float* op = out + (size_t)b * D + (size_t)d4 * 4;
        unsafeAtomicAdd(op + 0, acc[b].x);
        unsafeAtomicAdd(op + 1, acc[b].y);
        unsafeAtomicAdd(op + 2, acc[b].z);
        unsafeAtomicAdd(op + 3, acc[b].w);
    }
}

extern "C" void kernel_launch(void* const* d_in, const int* in_sizes, int n_in,
                              void* d_out, int out_size, void* d_ws, size_t ws_size,
                              hipStream_t stream) {
    const float* key = (const float*)d_in[0];   // [16, 512, 7, 7]
    const float* mem = (const float*)d_in[1];   // [2000, 512, 7, 7]
    float* out = (float*)d_out;                 // [16, 512, 7, 7]

    // Workspace layout (floats), 16B-aligned sections.
    float* ws = (float*)d_ws;
    unsigned short* ksw = (unsigned short*)ws;          // 2*NT*64*8 ush = 401408 fl
    float* dpart = ws + 401408;                         // KC*B*N = 512000
    float* mpart = dpart + (size_t)KC * B * N;          // KC*N   =  32000
    float* kn2   = mpart + (size_t)KC * N;              // 16
    float* w     = kn2 + 16;                            // B*N    =  32000
    float* part  = w + (size_t)B * N;                   // NCHUNK*B*D = 10035200
    const size_t need_full =
        (size_t)(401408 + (size_t)KC * B * N + KC * N + 16 + B * N + (size_t)NCHUNK * B * D) * 4;

    hipMemsetAsync(kn2, 0, 16 * sizeof(float), stream);
    k_split<<<dim3(NT * 64 / 256), 256, 0, stream>>>(key, ksw, kn2);
    k_dots<<<dim3(N / 16, 4), 256, 0, stream>>>(mem, ksw, dpart, mpart);
    k_softmax<<<dim3(B), 256, 0, stream>>>(kn2, dpart, mpart, w);
    if (ws_size >= need_full) {
        k_out_p<<<dim3((D4 + 255) / 256, NCHUNK), 256, 0, stream>>>((const float4*)mem, w, (float4*)part);
        k_reduce<<<dim3(B * D4 / 256), 256, 0, stream>>>((const float4*)part, (float4*)out);
    } else {
        hipMemsetAsync(d_out, 0, (size_t)B * D * sizeof(float), stream);
        k_out_atomic<<<dim3((D4 + 255) / 256, NCHUNK), 256, 0, stream>>>((const float4*)mem, w, out);
    }
}

// Round 6
// 353.834 us; speedup vs baseline: 1.4749x; 1.0154x over previous
//
#include <hip/hip_runtime.h>
#include <math.h>

#define B 16
#define N 2000
#define D 25088            // 512*7*7
#define D4 6272            // D/4
#define PI2 1.570795f      // 3.14159/2, matches the torch-module constant
#define KC 28              // K-chunks in k_dots (7 block-y x 4 waves)
#define KSPAN (D / KC)     // 896
#define KTILES (KSPAN / 32)// 28 MFMA k-steps per wave
#define NT (D / 32)        // 784 k-tiles total
#define NCHUNK 25
#define NPER (N / NCHUNK)  // 80
#define SELHI 0x07060302u  // v_perm selector: pack hi16(x0)|hi16(x1)<<16

typedef __attribute__((ext_vector_type(8))) short short8;   // 8 x bf16 frag
typedef __attribute__((ext_vector_type(4))) float f32x4;    // MFMA C/D
typedef unsigned int uint;

union pk { uint4 u; short8 s; };
__device__ __forceinline__ short8 as_s8(uint4 u) { pk p; p.u = u; return p.s; }

__device__ __forceinline__ float wave_sum(float v) {
#pragma unroll
    for (int off = 32; off > 0; off >>= 1) v += __shfl_xor(v, off, 64);
    return v;
}
__device__ __forceinline__ float wave_max(float v) {
#pragma unroll
    for (int off = 32; off > 0; off >>= 1) v = fmaxf(v, __shfl_xor(v, off, 64));
    return v;
}

// fp32x8 -> bf16 hi/lo fragments (truncation split; bit-identical to the
// verified R4/R5 path) + msq into 4 rotating accumulators (breaks the serial
// fma chain; packs as v_pk_fma_f32).
__device__ __forceinline__ void cvt_hilo(const float4& a, const float4& b,
                                         short8& hi, short8& lo, float4& msqv) {
    float xs[8] = {a.x, a.y, a.z, a.w, b.x, b.y, b.z, b.w};
    float* mq = &msqv.x;
    uint lu[8];
#pragma unroll
    for (int j = 0; j < 8; ++j) {
        uint u = __float_as_uint(xs[j]);
        float lof = xs[j] - __uint_as_float(u & 0xffff0000u);
        lu[j] = __float_as_uint(lof);
        mq[j & 3] = fmaf(xs[j], xs[j], mq[j & 3]);
    }
    uint4 h, l;
    h.x = __builtin_amdgcn_perm(__float_as_uint(xs[1]), __float_as_uint(xs[0]), SELHI);
    h.y = __builtin_amdgcn_perm(__float_as_uint(xs[3]), __float_as_uint(xs[2]), SELHI);
    h.z = __builtin_amdgcn_perm(__float_as_uint(xs[5]), __float_as_uint(xs[4]), SELHI);
    h.w = __builtin_amdgcn_perm(__float_as_uint(xs[7]), __float_as_uint(xs[6]), SELHI);
    l.x = __builtin_amdgcn_perm(lu[1], lu[0], SELHI);
    l.y = __builtin_amdgcn_perm(lu[3], lu[2], SELHI);
    l.z = __builtin_amdgcn_perm(lu[5], lu[4], SELHI);
    l.w = __builtin_amdgcn_perm(lu[7], lu[6], SELHI);
    hi = as_s8(h); lo = as_s8(l);
}

// ---------------------------------------------------------------------------
// k_split: key fp32 -> bf16 hi/lo planes in MFMA A-frag order; fuses the
// per-b ||key||^2 reduction into kn2[16] (zeroed before launch).
// ---------------------------------------------------------------------------
__global__ void k_split(const float* __restrict__ key, unsigned short* __restrict__ ksw,
                        float* __restrict__ kn2) {
    const int tid  = threadIdx.x;
    const int g    = blockIdx.x * 256 + tid;   // 0 .. NT*64-1
    const int tile = g >> 6, lane = g & 63;
    const int m = lane & 15, quad = lane >> 4;
    const float* src = key + (size_t)m * D + tile * 32 + quad * 8;
    float4 x0 = *(const float4*)src;
    float4 x1 = *(const float4*)(src + 4);
    short8 hi, lo;
    float4 msqv = {0.f, 0.f, 0.f, 0.f};
    cvt_hilo(x0, x1, hi, lo, msqv);
    pk ph; ph.s = hi;
    pk pl; pl.s = lo;
    *(uint4*)(ksw + ((size_t)tile * 64 + lane) * 8)        = ph.u;
    *(uint4*)(ksw + ((size_t)(NT + tile) * 64 + lane) * 8) = pl.u;

    float ssq = (msqv.x + msqv.y) + (msqv.z + msqv.w);
    ssq += __shfl_xor(ssq, 16, 64);
    ssq += __shfl_xor(ssq, 32, 64);
    __shared__ float lds[4][16];
    if (quad == 0) lds[tid >> 6][m] = ssq;
    __syncthreads();
    if (tid < 16)
        atomicAdd(&kn2[tid], lds[0][tid] + lds[1][tid] + lds[2][tid] + lds[3][tid]);
}

// ---------------------------------------------------------------------------
// k_dots (MFMA): dots[b][n] = key[b].mem[n], mn2[n] = ||mem[n]||^2.
// Grid (125, 7) x 4 waves = 3500 waves (~13.7/CU); wave = 16-row n-tile x
// 1/28th of K. Depth-2 register pipeline: 8 loads in flight per wave.
// ---------------------------------------------------------------------------
__global__ __launch_bounds__(256, 2) void k_dots(const float* __restrict__ mem,
                                                 const unsigned short* __restrict__ ksw,
                                                 float* __restrict__ dpart,
                                                 float* __restrict__ mpart) {
    const int tid  = threadIdx.x;
    const int lane = tid & 63;
    const int wave = tid >> 6;
    const int n0   = blockIdx.x * 16;
    const int kc   = blockIdx.y * 4 + wave;        // 0..27
    const int nrow = lane & 15, quad = lane >> 4;

    const float4* mrow4 = (const float4*)(mem + (size_t)(n0 + nrow) * D + kc * KSPAN) + quad * 2;
    const uint4* khp = (const uint4*)(ksw + ((size_t)(kc * KTILES) * 64 + lane) * 8);
    const uint4* klp = (const uint4*)(ksw + ((size_t)(NT + kc * KTILES) * 64 + lane) * 8);

    f32x4 ahh = {0.f, 0.f, 0.f, 0.f};
    f32x4 ahl = ahh, alh = ahh;
    float4 msqv = {0.f, 0.f, 0.f, 0.f};

    // Pipeline buffers: set A = step t, set B = step t+1.
    float4 a0 = mrow4[0], a1 = mrow4[1];
    uint4  ha = khp[0],   la = klp[0];
    float4 b0 = mrow4[8], b1 = mrow4[9];
    uint4  hb = khp[64],  lb = klp[64];

    for (int t = 0; t < KTILES; t += 2) {
        const int t2 = (t + 2 < KTILES) ? t + 2 : t;
        const int t3 = (t + 3 < KTILES) ? t + 3 : t;
        float4 na0 = mrow4[(size_t)t2 * 8], na1 = mrow4[(size_t)t2 * 8 + 1];
        uint4  nha = khp[(size_t)t2 * 64],  nla = klp[(size_t)t2 * 64];
        float4 nb0 = mrow4[(size_t)t3 * 8], nb1 = mrow4[(size_t)t3 * 8 + 1];
        uint4  nhb = khp[(size_t)t3 * 64],  nlb = klp[(size_t)t3 * 64];

        short8 bh, bl;
        cvt_hilo(a0, a1, bh, bl, msqv);
        {
            short8 kh = as_s8(ha), kl = as_s8(la);
            ahh = __builtin_amdgcn_mfma_f32_16x16x32_bf16(kh, bh, ahh, 0, 0, 0);
            ahl = __builtin_amdgcn_mfma_f32_16x16x32_bf16(kh, bl, ahl, 0, 0, 0);
            alh = __builtin_amdgcn_mfma_f32_16x16x32_bf16(kl, bh, alh, 0, 0, 0);
        }
        cvt_hilo(b0, b1, bh, bl, msqv);
        {
            short8 kh = as_s8(hb), kl = as_s8(lb);
            ahh = __builtin_amdgcn_mfma_f32_16x16x32_bf16(kh, bh, ahh, 0, 0, 0);
            ahl = __builtin_amdgcn_mfma_f32_16x16x32_bf16(kh, bl, ahl, 0, 0, 0);
            alh = __builtin_amdgcn_mfma_f32_16x16x32_bf16(kl, bh, alh, 0, 0, 0);
        }
        a0 = na0; a1 = na1; ha = nha; la = nla;
        b0 = nb0; b1 = nb1; hb = nhb; lb = nlb;
    }

    f32x4 dt;
#pragma unroll
    for (int r = 0; r < 4; ++r) dt[r] = ahh[r] + ahl[r] + alh[r];
    // C/D layout (m89-verified): col(n) = lane&15, row(b) = quad*4 + reg
#pragma unroll
    for (int r = 0; r < 4; ++r)
        dpart[((size_t)kc * B + quad * 4 + r) * N + n0 + nrow] = dt[r];

    float msq = (msqv.x + msqv.y) + (msqv.z + msqv.w);
    msq += __shfl_xor(msq, 16, 64);
    msq += __shfl_xor(msq, 32, 64);
    if (quad == 0) mpart[(size_t)kc * N + n0 + nrow] = msq;
}

// ---------------------------------------------------------------------------
// k_softmax: reduce K-partials, per-b softmax of tan(cos * PI/2).
// ---------------------------------------------------------------------------
__global__ __launch_bounds__(256, 2) void k_softmax(const float* __restrict__ kn2,
                                                    const float* __restrict__ dpart,
                                                    const float* __restrict__ mpart,
                                                    float* __restrict__ w) {
    const int b = blockIdx.x, tid = threadIdx.x;
    const int wv = tid >> 6, ln = tid & 63;
    __shared__ float t[N];
    __shared__ float redB[4], redC[4];

    const float kn = fmaxf(sqrtf(kn2[b]), 1e-8f);

    float mx = -1e30f;
    for (int n = tid; n < N; n += 256) {
        float ds = 0.f, ms = 0.f;
#pragma unroll
        for (int kc = 0; kc < KC; ++kc) {
            ds += dpart[((size_t)kc * B + b) * N + n];
            ms += mpart[(size_t)kc * N + n];
        }
        float mn = fmaxf(sqrtf(ms), 1e-8f);
        float tv = tanf(ds / (kn * mn) * PI2);
        t[n] = tv;
        mx = fmaxf(mx, tv);
    }
    mx = wave_max(mx);
    if (ln == 0) redB[wv] = mx;
    __syncthreads();
    mx = fmaxf(fmaxf(redB[0], redB[1]), fmaxf(redB[2], redB[3]));

    float sum = 0.f;
    for (int n = tid; n < N; n += 256) {
        float e = expf(t[n] - mx);
        t[n] = e;
        sum += e;
    }
    sum = wave_sum(sum);
    if (ln == 0) redC[wv] = sum;
    __syncthreads();
    sum = redC[0] + redC[1] + redC[2] + redC[3];
    const float inv = 1.f / sum;
    for (int n = tid; n < N; n += 256) w[(size_t)b * N + n] = t[n] * inv;
}

// ---------------------------------------------------------------------------
// k_out partials: part[c][b][d] = sum_{n in chunk c} w[b][n]*mem[n][d].
// Grid (25, NCHUNK) x 256 thr; unrolled groups of 8 with next-group prefetch.
// ---------------------------------------------------------------------------
__global__ __launch_bounds__(256, 2) void k_out_p(const float4* __restrict__ mem,
                                                  const float* __restrict__ w,
                                                  float4* __restrict__ part) {
    const int tid = threadIdx.x;
    const int d4  = blockIdx.x * 256 + tid;
    const int n0  = blockIdx.y * NPER;

    __shared__ float wt[B * NPER];   // 16 x 80
    for (int i = tid; i < B * NPER; i += 256)
        wt[i] = w[(size_t)(i / NPER) * N + n0 + (i % NPER)];
    __syncthreads();
    if (d4 >= D4) return;

    const float4* mp = mem + (size_t)n0 * D4 + d4;
    float4 acc[B];
#pragma unroll
    for (int b = 0; b < B; ++b) acc[b] = make_float4(0.f, 0.f, 0.f, 0.f);

    float4 cur[8];
#pragma unroll
    for (int u = 0; u < 8; ++u) cur[u] = mp[(size_t)u * D4];

#pragma unroll
    for (int g = 0; g < NPER / 8; ++g) {
        const int gn = (g + 1 < NPER / 8) ? g + 1 : g;
        float4 nxt[8];
#pragma unroll
        for (int u = 0; u < 8; ++u) nxt[u] = mp[(size_t)(gn * 8 + u) * D4];
#pragma unroll
        for (int b = 0; b < B; ++b) {
            float4 a = acc[b];
#pragma unroll
            for (int u = 0; u < 8; ++u) {
                const float wv = wt[b * NPER + g * 8 + u];
                a.x = fmaf(wv, cur[u].x, a.x); a.y = fmaf(wv, cur[u].y, a.y);
                a.z = fmaf(wv, cur[u].z, a.z); a.w = fmaf(wv, cur[u].w, a.w);
            }
            acc[b] = a;
        }
#pragma unroll
        for (int u = 0; u < 8; ++u) cur[u] = nxt[u];
    }
#pragma unroll
    for (int b = 0; b < B; ++b)
        part[((size_t)blockIdx.y * B + b) * D4 + d4] = acc[b];
}

__global__ void k_reduce(const float4* __restrict__ part, float4* __restrict__ out) {
    const int i = blockIdx.x * 256 + threadIdx.x;   // < B*D4 = 100352
    float4 s = part[i];
#pragma unroll
    for (int c = 1; c < NCHUNK; ++c) {
        float4 p = part[(size_t)c * B * D4 + i];
        s.x += p.x; s.y += p.y; s.z += p.z; s.w += p.w;
    }
    out[i] = s;
}

// Atomic fallback if workspace is too small for partials.
__global__ __launch_bounds__(256, 2) void k_out_atomic(const float4* __restrict__ mem,
                                                       const float* __restrict__ w,
                                                       float* __restrict__ out) {
    const int tid = threadIdx.x;
    const int d4  = blockIdx.x * 256 + tid;
    const int n0  = blockIdx.y * NPER;
    __shared__ float wt[B * NPER];
    for (int i = tid; i < B * NPER; i += 256)
        wt[i] = w[(size_t)(i / NPER) * N + n0 + (i % NPER)];
    __syncthreads();
    if (d4 >= D4) return;
    const float4* mp = mem + (size_t)n0 * D4 + d4;
    float4 acc[B];
#pragma unroll
    for (int b = 0; b < B; ++b) acc[b] = make_float4(0.f, 0.f, 0.f, 0.f);
    for (int n = 0; n < NPER; n += 8) {
        float4 mv[8];
#pragma unroll
        for (int u = 0; u < 8; ++u) mv[u] = mp[(size_t)(n + u) * D4];
#pragma unroll
        for (int b = 0; b < B; ++b) {
            float4 a = acc[b];
#pragma unroll
            for (int u = 0; u < 8; ++u) {
                const float wv = wt[b * NPER + n + u];
                a.x = fmaf(wv, mv[u].x, a.x); a.y = fmaf(wv, mv[u].y, a.y);
                a.z = fmaf(wv, mv[u].z, a.z); a.w = fmaf(wv, mv[u].w, a.w);
            }
            acc[b] = a;
        }
    }
#pragma unroll
    for (int b = 0; b < B; ++b) {
        float* op = out + (size_t)b * D + (size_t)d4 * 4;
        unsafeAtomicAdd(op + 0, acc[b].x);
        unsafeAtomicAdd(op + 1, acc[b].y);
        unsafeAtomicAdd(op + 2, acc[b].z);
        unsafeAtomicAdd(op + 3, acc[b].w);
    }
}

extern "C" void kernel_launch(void* const* d_in, const int* in_sizes, int n_in,
                              void* d_out, int out_size, void* d_ws, size_t ws_size,
                              hipStream_t stream) {
    const float* key = (const float*)d_in[0];   // [16, 512, 7, 7]
    const float* mem = (const float*)d_in[1];   // [2000, 512, 7, 7]
    float* out = (float*)d_out;                 // [16, 512, 7, 7]

    // Workspace layout (floats), 16B-aligned sections.
    float* ws = (float*)d_ws;
    unsigned short* ksw = (unsigned short*)ws;          // 2*NT*64*8 ush = 401408 fl
    float* dpart = ws + 401408;                         // KC*B*N = 896000
    float* mpart = dpart + (size_t)KC * B * N;          // KC*N   =  56000
    float* kn2   = mpart + (size_t)KC * N;              // 16
    float* w     = kn2 + 16;                            // B*N    =  32000
    float* part  = w + (size_t)B * N;                   // NCHUNK*B*D = 10035200
    const size_t need_full =
        (size_t)(401408 + (size_t)KC * B * N + (size_t)KC * N + 16 + B * N +
                 (size_t)NCHUNK * B * D) * 4;

    hipMemsetAsync(kn2, 0, 16 * sizeof(float), stream);
    k_split<<<dim3(NT * 64 / 256), 256, 0, stream>>>(key, ksw, kn2);
    k_dots<<<dim3(N / 16, KC / 4), 256, 0, stream>>>(mem, ksw, dpart, mpart);
    k_softmax<<<dim3(B), 256, 0, stream>>>(kn2, dpart, mpart, w);
    if (ws_size >= need_full) {
        k_out_p<<<dim3((D4 + 255) / 256, NCHUNK), 256, 0, stream>>>((const float4*)mem, w, (float4*)part);
        k_reduce<<<dim3(B * D4 / 256), 256, 0, stream>>>((const float4*)part, (float4*)out);
    } else {
        hipMemsetAsync(d_out, 0, (size_t)B * D * sizeof(float), stream);
        k_out_atomic<<<dim3((D4 + 255) / 256, NCHUNK), 256, 0, stream>>>((const float4*)mem, w, out);
    }
}

// Round 7
// 343.654 us; speedup vs baseline: 1.5186x; 1.0296x over previous
//
#include <hip/hip_runtime.h>
#include <math.h>

#define B 16
#define N 2000
#define D 25088            // 512*7*7
#define D4 6272            // D/4
#define PI2 1.570795f      // 3.14159/2, matches the torch-module constant
#define KC 28              // K-chunks in k_dots (7 block-y x 4 waves)
#define KSPAN (D / KC)     // 896
#define KTILES (KSPAN / 32)// 28 MFMA k-steps per wave
#define NT (D / 32)        // 784 k-tiles total
#define NCHUNK 25
#define NPER (N / NCHUNK)  // 80
#define SELHI 0x07060302u  // v_perm selector: pack hi16(x0)|hi16(x1)<<16

typedef __attribute__((ext_vector_type(8))) short short8;   // 8 x bf16 frag
typedef __attribute__((ext_vector_type(4))) float f32x4;    // MFMA C/D
typedef unsigned int uint;

union pk { uint4 u; short8 s; };
__device__ __forceinline__ short8 as_s8(uint4 u) { pk p; p.u = u; return p.s; }

__device__ __forceinline__ float wave_sum(float v) {
#pragma unroll
    for (int off = 32; off > 0; off >>= 1) v += __shfl_xor(v, off, 64);
    return v;
}
__device__ __forceinline__ float wave_max(float v) {
#pragma unroll
    for (int off = 32; off > 0; off >>= 1) v = fmaxf(v, __shfl_xor(v, off, 64));
    return v;
}

// fp32x8 -> bf16 hi/lo fragments (truncation split; verified R4-R6) + msq into
// 4 rotating accumulators (breaks the serial fma chain).
__device__ __forceinline__ void cvt_hilo(const float4& a, const float4& b,
                                         short8& hi, short8& lo, float4& msqv) {
    float xs[8] = {a.x, a.y, a.z, a.w, b.x, b.y, b.z, b.w};
    float* mq = &msqv.x;
    uint lu[8];
#pragma unroll
    for (int j = 0; j < 8; ++j) {
        uint u = __float_as_uint(xs[j]);
        float lof = xs[j] - __uint_as_float(u & 0xffff0000u);
        lu[j] = __float_as_uint(lof);
        mq[j & 3] = fmaf(xs[j], xs[j], mq[j & 3]);
    }
    uint4 h, l;
    h.x = __builtin_amdgcn_perm(__float_as_uint(xs[1]), __float_as_uint(xs[0]), SELHI);
    h.y = __builtin_amdgcn_perm(__float_as_uint(xs[3]), __float_as_uint(xs[2]), SELHI);
    h.z = __builtin_amdgcn_perm(__float_as_uint(xs[5]), __float_as_uint(xs[4]), SELHI);
    h.w = __builtin_amdgcn_perm(__float_as_uint(xs[7]), __float_as_uint(xs[6]), SELHI);
    l.x = __builtin_amdgcn_perm(lu[1], lu[0], SELHI);
    l.y = __builtin_amdgcn_perm(lu[3], lu[2], SELHI);
    l.z = __builtin_amdgcn_perm(lu[5], lu[4], SELHI);
    l.w = __builtin_amdgcn_perm(lu[7], lu[6], SELHI);
    hi = as_s8(h); lo = as_s8(l);
}

// ---------------------------------------------------------------------------
// k_split: key fp32 -> bf16 hi/lo planes in MFMA A-frag order; fuses the
// per-b ||key||^2 reduction into kn2[16] (zeroed before launch).
// ---------------------------------------------------------------------------
__global__ void k_split(const float* __restrict__ key, unsigned short* __restrict__ ksw,
                        float* __restrict__ kn2) {
    const int tid  = threadIdx.x;
    const int g    = blockIdx.x * 256 + tid;   // 0 .. NT*64-1
    const int tile = g >> 6, lane = g & 63;
    const int m = lane & 15, quad = lane >> 4;
    const float* src = key + (size_t)m * D + tile * 32 + quad * 8;
    float4 x0 = *(const float4*)src;
    float4 x1 = *(const float4*)(src + 4);
    short8 hi, lo;
    float4 msqv = {0.f, 0.f, 0.f, 0.f};
    cvt_hilo(x0, x1, hi, lo, msqv);
    pk ph; ph.s = hi;
    pk pl; pl.s = lo;
    *(uint4*)(ksw + ((size_t)tile * 64 + lane) * 8)        = ph.u;
    *(uint4*)(ksw + ((size_t)(NT + tile) * 64 + lane) * 8) = pl.u;

    float ssq = (msqv.x + msqv.y) + (msqv.z + msqv.w);
    ssq += __shfl_xor(ssq, 16, 64);
    ssq += __shfl_xor(ssq, 32, 64);
    __shared__ float lds[4][16];
    if (quad == 0) lds[tid >> 6][m] = ssq;
    __syncthreads();
    if (tid < 16)
        atomicAdd(&kn2[tid], lds[0][tid] + lds[1][tid] + lds[2][tid] + lds[3][tid]);
}

// ---------------------------------------------------------------------------
// k_dots (MFMA): dots[b][n] += key[b].mem[n] (this wave's K-chunk),
// mn2[n] += ||mem[n]||^2 chunk. Grid (125, 7) x 4 waves; depth-2 register
// pipeline. Results go straight to dots/mn2 with fp32 HW atomics (28-way
// contention per address) -- no dpart buffer, no gather in softmax.
// ---------------------------------------------------------------------------
__global__ __launch_bounds__(256, 2) void k_dots(const float* __restrict__ mem,
                                                 const unsigned short* __restrict__ ksw,
                                                 float* __restrict__ dots,
                                                 float* __restrict__ mn2) {
    const int tid  = threadIdx.x;
    const int lane = tid & 63;
    const int wave = tid >> 6;
    const int n0   = blockIdx.x * 16;
    const int kc   = blockIdx.y * 4 + wave;        // 0..27
    const int nrow = lane & 15, quad = lane >> 4;

    const float4* mrow4 = (const float4*)(mem + (size_t)(n0 + nrow) * D + kc * KSPAN) + quad * 2;
    const uint4* khp = (const uint4*)(ksw + ((size_t)(kc * KTILES) * 64 + lane) * 8);
    const uint4* klp = (const uint4*)(ksw + ((size_t)(NT + kc * KTILES) * 64 + lane) * 8);

    f32x4 ahh = {0.f, 0.f, 0.f, 0.f};
    f32x4 ahl = ahh, alh = ahh;
    float4 msqv = {0.f, 0.f, 0.f, 0.f};

    float4 a0 = mrow4[0], a1 = mrow4[1];
    uint4  ha = khp[0],   la = klp[0];
    float4 b0 = mrow4[8], b1 = mrow4[9];
    uint4  hb = khp[64],  lb = klp[64];

    for (int t = 0; t < KTILES; t += 2) {
        const int t2 = (t + 2 < KTILES) ? t + 2 : t;
        const int t3 = (t + 3 < KTILES) ? t + 3 : t;
        float4 na0 = mrow4[(size_t)t2 * 8], na1 = mrow4[(size_t)t2 * 8 + 1];
        uint4  nha = khp[(size_t)t2 * 64],  nla = klp[(size_t)t2 * 64];
        float4 nb0 = mrow4[(size_t)t3 * 8], nb1 = mrow4[(size_t)t3 * 8 + 1];
        uint4  nhb = khp[(size_t)t3 * 64],  nlb = klp[(size_t)t3 * 64];

        short8 bh, bl;
        cvt_hilo(a0, a1, bh, bl, msqv);
        {
            short8 kh = as_s8(ha), kl = as_s8(la);
            ahh = __builtin_amdgcn_mfma_f32_16x16x32_bf16(kh, bh, ahh, 0, 0, 0);
            ahl = __builtin_amdgcn_mfma_f32_16x16x32_bf16(kh, bl, ahl, 0, 0, 0);
            alh = __builtin_amdgcn_mfma_f32_16x16x32_bf16(kl, bh, alh, 0, 0, 0);
        }
        cvt_hilo(b0, b1, bh, bl, msqv);
        {
            short8 kh = as_s8(hb), kl = as_s8(lb);
            ahh = __builtin_amdgcn_mfma_f32_16x16x32_bf16(kh, bh, ahh, 0, 0, 0);
            ahl = __builtin_amdgcn_mfma_f32_16x16x32_bf16(kh, bl, ahl, 0, 0, 0);
            alh = __builtin_amdgcn_mfma_f32_16x16x32_bf16(kl, bh, alh, 0, 0, 0);
        }
        a0 = na0; a1 = na1; ha = nha; la = nla;
        b0 = nb0; b1 = nb1; hb = nhb; lb = nlb;
    }

    // C/D layout (m89-verified): col(n) = lane&15, row(b) = quad*4 + reg
#pragma unroll
    for (int r = 0; r < 4; ++r)
        unsafeAtomicAdd(&dots[(size_t)(quad * 4 + r) * N + n0 + nrow],
                        ahh[r] + ahl[r] + alh[r]);

    float msq = (msqv.x + msqv.y) + (msqv.z + msqv.w);
    msq += __shfl_xor(msq, 16, 64);
    msq += __shfl_xor(msq, 32, 64);
    if (quad == 0) unsafeAtomicAdd(&mn2[n0 + nrow], msq);
}

// ---------------------------------------------------------------------------
// k_softmax: per-b softmax of tan(cos * PI/2) from pre-reduced dots/mn2.
// Small coalesced reads only (~136 KB total).
// ---------------------------------------------------------------------------
__global__ __launch_bounds__(256, 2) void k_softmax(const float* __restrict__ kn2,
                                                    const float* __restrict__ dots,
                                                    const float* __restrict__ mn2,
                                                    float* __restrict__ w) {
    const int b = blockIdx.x, tid = threadIdx.x;
    const int wv = tid >> 6, ln = tid & 63;
    __shared__ float t[N];
    __shared__ float redB[4], redC[4];

    const float kn = fmaxf(sqrtf(kn2[b]), 1e-8f);

    float mx = -1e30f;
    for (int n = tid; n < N; n += 256) {
        float mn = fmaxf(sqrtf(mn2[n]), 1e-8f);
        float tv = tanf(dots[(size_t)b * N + n] / (kn * mn) * PI2);
        t[n] = tv;
        mx = fmaxf(mx, tv);
    }
    mx = wave_max(mx);
    if (ln == 0) redB[wv] = mx;
    __syncthreads();
    mx = fmaxf(fmaxf(redB[0], redB[1]), fmaxf(redB[2], redB[3]));

    float sum = 0.f;
    for (int n = tid; n < N; n += 256) {
        float e = expf(t[n] - mx);
        t[n] = e;
        sum += e;
    }
    sum = wave_sum(sum);
    if (ln == 0) redC[wv] = sum;
    __syncthreads();
    sum = redC[0] + redC[1] + redC[2] + redC[3];
    const float inv = 1.f / sum;
    for (int n = tid; n < N; n += 256) w[(size_t)b * N + n] = t[n] * inv;
}

// ---------------------------------------------------------------------------
// k_out partials: part[c][b][d] = sum_{n in chunk c} w[b][n]*mem[n][d].
// Grid (25, NCHUNK) x 256; group-of-8 prefetch; w read from LDS as float4
// (2 ds_read_b128 per (b,group) instead of 8 ds_read_b32).
// ---------------------------------------------------------------------------
__global__ __launch_bounds__(256, 2) void k_out_p(const float4* __restrict__ mem,
                                                  const float* __restrict__ w,
                                                  float4* __restrict__ part) {
    const int tid = threadIdx.x;
    const int d4  = blockIdx.x * 256 + tid;
    const int n0  = blockIdx.y * NPER;

    __shared__ float wt[B * NPER];   // 16 x 80
    for (int i = tid; i < B * NPER; i += 256)
        wt[i] = w[(size_t)(i / NPER) * N + n0 + (i % NPER)];
    __syncthreads();
    if (d4 >= D4) return;

    const float4* mp = mem + (size_t)n0 * D4 + d4;
    float4 acc[B];
#pragma unroll
    for (int b = 0; b < B; ++b) acc[b] = make_float4(0.f, 0.f, 0.f, 0.f);

    float4 cur[8];
#pragma unroll
    for (int u = 0; u < 8; ++u) cur[u] = mp[(size_t)u * D4];

#pragma unroll
    for (int g = 0; g < NPER / 8; ++g) {
        const int gn = (g + 1 < NPER / 8) ? g + 1 : g;
        float4 nxt[8];
#pragma unroll
        for (int u = 0; u < 8; ++u) nxt[u] = mp[(size_t)(gn * 8 + u) * D4];
#pragma unroll
        for (int b = 0; b < B; ++b) {
            const float4* wp = (const float4*)(wt + b * NPER) + g * 2;
            float4 w0 = wp[0], w1 = wp[1];
            float4 a = acc[b];
            a.x = fmaf(w0.x, cur[0].x, a.x); a.y = fmaf(w0.x, cur[0].y, a.y);
            a.z = fmaf(w0.x, cur[0].z, a.z); a.w = fmaf(w0.x, cur[0].w, a.w);
            a.x = fmaf(w0.y, cur[1].x, a.x); a.y = fmaf(w0.y, cur[1].y, a.y);
            a.z = fmaf(w0.y, cur[1].z, a.z); a.w = fmaf(w0.y, cur[1].w, a.w);
            a.x = fmaf(w0.z, cur[2].x, a.x); a.y = fmaf(w0.z, cur[2].y, a.y);
            a.z = fmaf(w0.z, cur[2].z, a.z); a.w = fmaf(w0.z, cur[2].w, a.w);
            a.x = fmaf(w0.w, cur[3].x, a.x); a.y = fmaf(w0.w, cur[3].y, a.y);
            a.z = fmaf(w0.w, cur[3].z, a.z); a.w = fmaf(w0.w, cur[3].w, a.w);
            a.x = fmaf(w1.x, cur[4].x, a.x); a.y = fmaf(w1.x, cur[4].y, a.y);
            a.z = fmaf(w1.x, cur[4].z, a.z); a.w = fmaf(w1.x, cur[4].w, a.w);
            a.x = fmaf(w1.y, cur[5].x, a.x); a.y = fmaf(w1.y, cur[5].y, a.y);
            a.z = fmaf(w1.y, cur[5].z, a.z); a.w = fmaf(w1.y, cur[5].w, a.w);
            a.x = fmaf(w1.z, cur[6].x, a.x); a.y = fmaf(w1.z, cur[6].y, a.y);
            a.z = fmaf(w1.z, cur[6].z, a.z); a.w = fmaf(w1.z, cur[6].w, a.w);
            a.x = fmaf(w1.w, cur[7].x, a.x); a.y = fmaf(w1.w, cur[7].y, a.y);
            a.z = fmaf(w1.w, cur[7].z, a.z); a.w = fmaf(w1.w, cur[7].w, a.w);
            acc[b] = a;
        }
#pragma unroll
        for (int u = 0; u < 8; ++u) cur[u] = nxt[u];
    }
#pragma unroll
    for (int b = 0; b < B; ++b)
        part[((size_t)blockIdx.y * B + b) * D4 + d4] = acc[b];
}

__global__ void k_reduce(const float4* __restrict__ part, float4* __restrict__ out) {
    const int i = blockIdx.x * 256 + threadIdx.x;   // < B*D4 = 100352
    float4 s = part[i];
#pragma unroll
    for (int c = 1; c < NCHUNK; ++c) {
        float4 p = part[(size_t)c * B * D4 + i];
        s.x += p.x; s.y += p.y; s.z += p.z; s.w += p.w;
    }
    out[i] = s;
}

// Atomic fallback if workspace is too small for partials.
__global__ __launch_bounds__(256, 2) void k_out_atomic(const float4* __restrict__ mem,
                                                       const float* __restrict__ w,
                                                       float* __restrict__ out) {
    const int tid = threadIdx.x;
    const int d4  = blockIdx.x * 256 + tid;
    const int n0  = blockIdx.y * NPER;
    __shared__ float wt[B * NPER];
    for (int i = tid; i < B * NPER; i += 256)
        wt[i] = w[(size_t)(i / NPER) * N + n0 + (i % NPER)];
    __syncthreads();
    if (d4 >= D4) return;
    const float4* mp = mem + (size_t)n0 * D4 + d4;
    float4 acc[B];
#pragma unroll
    for (int b = 0; b < B; ++b) acc[b] = make_float4(0.f, 0.f, 0.f, 0.f);
    for (int n = 0; n < NPER; n += 8) {
        float4 mv[8];
#pragma unroll
        for (int u = 0; u < 8; ++u) mv[u] = mp[(size_t)(n + u) * D4];
#pragma unroll
        for (int b = 0; b < B; ++b) {
            float4 a = acc[b];
#pragma unroll
            for (int u = 0; u < 8; ++u) {
                const float wv = wt[b * NPER + n + u];
                a.x = fmaf(wv, mv[u].x, a.x); a.y = fmaf(wv, mv[u].y, a.y);
                a.z = fmaf(wv, mv[u].z, a.z); a.w = fmaf(wv, mv[u].w, a.w);
            }
            acc[b] = a;
        }
    }
#pragma unroll
    for (int b = 0; b < B; ++b) {
        float* op = out + (size_t)b * D + (size_t)d4 * 4;
        unsafeAtomicAdd(op + 0, acc[b].x);
        unsafeAtomicAdd(op + 1, acc[b].y);
        unsafeAtomicAdd(op + 2, acc[b].z);
        unsafeAtomicAdd(op + 3, acc[b].w);
    }
}

extern "C" void kernel_launch(void* const* d_in, const int* in_sizes, int n_in,
                              void* d_out, int out_size, void* d_ws, size_t ws_size,
                              hipStream_t stream) {
    const float* key = (const float*)d_in[0];   // [16, 512, 7, 7]
    const float* mem = (const float*)d_in[1];   // [2000, 512, 7, 7]
    float* out = (float*)d_out;                 // [16, 512, 7, 7]

    // Workspace layout (floats), 16B-aligned sections.
    float* ws = (float*)d_ws;
    unsigned short* ksw = (unsigned short*)ws;          // 2*NT*64*8 ush = 401408 fl
    float* dots  = ws + 401408;                         // B*N = 32000
    float* mn2   = dots + (size_t)B * N;                // N   =  2000
    float* kn2   = mn2 + N;                             // 16
    float* w     = kn2 + 16;                            // B*N =  32000
    float* part  = w + (size_t)B * N;                   // NCHUNK*B*D = 10035200
    const size_t need_full =
        (size_t)(401408 + B * N + N + 16 + B * N + (size_t)NCHUNK * B * D) * 4;

    // One memset zeroes dots + mn2 + kn2 (contiguous, 136 KB).
    hipMemsetAsync(dots, 0, (size_t)(B * N + N + 16) * sizeof(float), stream);
    k_split<<<dim3(NT * 64 / 256), 256, 0, stream>>>(key, ksw, kn2);
    k_dots<<<dim3(N / 16, KC / 4), 256, 0, stream>>>(mem, ksw, dots, mn2);
    k_softmax<<<dim3(B), 256, 0, stream>>>(kn2, dots, mn2, w);
    if (ws_size >= need_full) {
        k_out_p<<<dim3((D4 + 255) / 256, NCHUNK), 256, 0, stream>>>((const float4*)mem, w, (float4*)part);
        k_reduce<<<dim3(B * D4 / 256), 256, 0, stream>>>((const float4*)part, (float4*)out);
    } else {
        hipMemsetAsync(d_out, 0, (size_t)B * D * sizeof(float), stream);
        k_out_atomic<<<dim3((D4 + 255) / 256, NCHUNK), 256, 0, stream>>>((const float4*)mem, w, out);
    }
}